// Round 2
// baseline (103.429 us; speedup 1.0000x reference)
//
#include <hip/hip_runtime.h>
#include <math.h>

#define TB   256
#define HH   128      // input H=W
#define OHW  64       // output H=W
#define TR   16       // output rows per tile
#define NT   4        // tiles per plane (64/16)
#define XR   37       // input rows staged: 2*TR+5
#define XC   136      // 128 cols + pad (col offset +4, zeros in pad)
#define N0C  68       // n0 tile row stride

__device__ __forceinline__ float sigmoidf(float z) {
    return 1.0f / (1.0f + __expf(-z));
}

__global__ __launch_bounds__(TB) void fused_densenet_kernel(
    const float* __restrict__ x,
    const float* __restrict__ maxgate,
    const float* __restrict__ mb,
    const float* __restrict__ pconvs,
    const float* __restrict__ pbs,
    const float* __restrict__ pgates,
    const float* __restrict__ gbs,
    float* __restrict__ out)
{
    __shared__ float xs[XR][XC];          // input slab, zero-padded
    __shared__ float n0s[TR + 2][N0C];    // n0 with 1-halo (18 x 66 used)

    const int t     = threadIdx.x;
    const int bid   = blockIdx.x;
    const int tile  = bid & (NT - 1);
    const int plane = bid >> 2;           // b*256 + c
    const int c     = plane & 255;
    const int r0    = tile * TR;          // first global output row of tile

    // ---- uniform weights/biases (block-uniform index -> scalar loads) ----
    // ws rows: 0=maxgate 1=p0 2=p1 3=p2 4=p3 5=gate0 6=gate2(leaf1+node)
    float ws[7][9];
#pragma unroll
    for (int i = 0; i < 9; ++i) {
        ws[0][i] = maxgate[c * 9  + i];
        ws[1][i] = pconvs [c * 36 + i * 4 + 0];
        ws[2][i] = pconvs [c * 36 + i * 4 + 1];
        ws[3][i] = pconvs [c * 36 + i * 4 + 2];
        ws[4][i] = pconvs [c * 36 + i * 4 + 3];
        ws[5][i] = pgates [c * 27 + i * 3 + 0];
        ws[6][i] = pgates [c * 27 + i * 3 + 2];
    }
    const float bmax = mb[c];
    const float bp0 = pbs[c * 4 + 0], bp1 = pbs[c * 4 + 1];
    const float bp2 = pbs[c * 4 + 2], bp3 = pbs[c * 4 + 3];
    const float bg0 = gbs[c * 3 + 0];   // leaf0 gate bias
    const float bg1 = gbs[c * 3 + 1];   // leaf1 gate bias
    const float bg2 = gbs[c * 3 + 2];   // node gate bias

    // ---- global -> LDS: rows [2*r0-3 , 2*r0+33], cols -4..131 (zero pad) ----
    const float* xplane = x + (size_t)plane * (HH * HH);
    const int ir0 = 2 * r0 - 3;
    for (int s = t; s < XR * 34; s += TB) {       // 34 float4 slots per row
        const int rr = s / 34;
        const int qq = s - rr * 34;
        float4 v = make_float4(0.f, 0.f, 0.f, 0.f);
        const int ir = ir0 + rr;
        if (qq >= 1 && qq <= 32 && (unsigned)ir < (unsigned)HH) {
            v = *reinterpret_cast<const float4*>(xplane + ir * HH + (qq - 1) * 4);
        }
        *reinterpret_cast<float4*>(&xs[rr][qq * 4]) = v;   // 16B-aligned
    }
    __syncthreads();

    // ---- halo ring of n0 (18x66 grid minus 16x64 interior = 164 positions) ----
    if (t < 164) {
        int lr, lc;
        if (t < 66)        { lr = 0;  lc = t;       }
        else if (t < 132)  { lr = 17; lc = t - 66;  }
        else { const int i = t - 132; lr = 1 + (i >> 1); lc = (i & 1) ? 65 : 0; }
        const int gr = r0 - 1 + lr;   // global output row of this n0 entry
        const int gc = lc - 1;        // global output col
        float n0v = 0.f;              // stage-2 conv zero-pads n0 at image edge
        if ((unsigned)gr < (unsigned)OHW && (unsigned)gc < (unsigned)OHW) {
            float ag = 0.f, a0 = 0.f, a1 = 0.f;
#pragma unroll
            for (int dr = 0; dr < 3; ++dr)
#pragma unroll
                for (int dc = 0; dc < 3; ++dc) {
                    const float v = xs[2 * lr + dr][2 * lc + dc + 1];
                    const int i = dr * 3 + dc;
                    ag += v * ws[5][i];
                    a0 += v * ws[1][i];
                    a1 += v * ws[2][i];
                }
            const float sg = sigmoidf(ag + bg0);
            n0v = sg * (a0 + bp0) + (1.f - sg) * (a1 + bp1);
        }
        n0s[lr][lc] = n0v;
    }

    // ---- interior: 2x2 outputs per thread, 5x5 shared window ----
    const int p   = t & 31;           // col-pair index: out cols {2p, 2p+1}
    const int q   = t >> 5;           // row-pair index: out rows {2q, 2q+1} (local)
    const int grA = r0 + 2 * q;       // global out row A (row B = grA+1, always >=1)

    float acc[7][4];                  // [conv][o]: o = {A0,A1,B0,B1}
#pragma unroll
    for (int ci = 0; ci < 7; ++ci)
#pragma unroll
        for (int o = 0; o < 4; ++o) acc[ci][o] = 0.f;
    float mp0 = -INFINITY, mp1 = -INFINITY, mp2 = -INFINITY, mp3 = -INFINITY;

#pragma unroll
    for (int rr = 0; rr < 5; ++rr) {
        const int xr = 4 * q + 2 + rr;            // xs row
        const float  v0 = xs[xr][4 * p + 3];      // window col 0 (input col 4p-1)
        const float4 vv = *reinterpret_cast<const float4*>(&xs[xr][4 * p + 4]);
        const float v1 = vv.x, v2 = vv.y, v3 = vv.z, v4 = vv.w;

        // maxpool horizontal max3 (pad = -inf; only left edge can be OOB)
        const float v0m = (p == 0) ? -INFINITY : v0;
        const float h0  = fmaxf(fmaxf(v0m, v1), v2);
        const float h1  = fmaxf(fmaxf(v2, v3), v4);

        if (rr <= 2) {                            // out row A, weight row rr
            const float h0a = (rr == 0 && grA == 0) ? -INFINITY : h0;
            const float h1a = (rr == 0 && grA == 0) ? -INFINITY : h1;
            mp0 = fmaxf(mp0, h0a);
            mp1 = fmaxf(mp1, h1a);
#pragma unroll
            for (int ci = 0; ci < 7; ++ci) {
                acc[ci][0] += v0 * ws[ci][3 * rr] + v1 * ws[ci][3 * rr + 1] + v2 * ws[ci][3 * rr + 2];
                acc[ci][1] += v2 * ws[ci][3 * rr] + v3 * ws[ci][3 * rr + 1] + v4 * ws[ci][3 * rr + 2];
            }
        }
        if (rr >= 2) {                            // out row B, weight row rr-2
            const int kr = rr - 2;
            mp2 = fmaxf(mp2, h0);
            mp3 = fmaxf(mp3, h1);
#pragma unroll
            for (int ci = 0; ci < 7; ++ci) {
                acc[ci][2] += v0 * ws[ci][3 * kr] + v1 * ws[ci][3 * kr + 1] + v2 * ws[ci][3 * kr + 2];
                acc[ci][3] += v2 * ws[ci][3 * kr] + v3 * ws[ci][3 * kr + 1] + v4 * ws[ci][3 * kr + 2];
            }
        }
    }

    const float mpv[4] = { mp0, mp1, mp2, mp3 };
    float out1[4], n1v[4], n0v[4];
#pragma unroll
    for (int o = 0; o < 4; ++o) {
        const float sg0 = sigmoidf(acc[5][o] + bg0);
        n0v[o] = sg0 * (acc[1][o] + bp0) + (1.f - sg0) * (acc[2][o] + bp1);
        const float sg1 = sigmoidf(acc[6][o] + bg1);   // leaf1 gate: bias gbs[:,1]
        n1v[o]  = sg1 * (acc[3][o] + bp2) + (1.f - sg1) * (acc[4][o] + bp3);
        out1[o] = mpv[o] * (acc[0][o] + bmax);
    }
    // n0 interior write: rows {2q+1, 2q+2}, cols {2p+1, 2p+2} (halo offset +1)
    n0s[2 * q + 1][2 * p + 1] = n0v[0];
    n0s[2 * q + 1][2 * p + 2] = n0v[1];
    n0s[2 * q + 2][2 * p + 1] = n0v[2];
    n0s[2 * q + 2][2 * p + 2] = n0v[3];
    __syncthreads();

    // ---- stage 2: node gate conv on n0 (stride 1, pad 1) + combine + store ----
    float n0w[4][4];
#pragma unroll
    for (int r = 0; r < 4; ++r) {
        const float2 a = *reinterpret_cast<const float2*>(&n0s[2 * q + r][2 * p]);
        const float2 b = *reinterpret_cast<const float2*>(&n0s[2 * q + r][2 * p + 2]);
        n0w[r][0] = a.x; n0w[r][1] = a.y; n0w[r][2] = b.x; n0w[r][3] = b.y;
    }
    float ag[4] = { 0.f, 0.f, 0.f, 0.f };
#pragma unroll
    for (int kr = 0; kr < 3; ++kr)
#pragma unroll
        for (int kc = 0; kc < 3; ++kc) {
            const float w = ws[6][kr * 3 + kc];
            ag[0] += n0w[kr][kc]         * w;
            ag[1] += n0w[kr][kc + 1]     * w;
            ag[2] += n0w[kr + 1][kc]     * w;
            ag[3] += n0w[kr + 1][kc + 1] * w;
        }
    const float n0c[4] = { n0w[1][1], n0w[1][2], n0w[2][1], n0w[2][2] };

    float res[4];
#pragma unroll
    for (int o = 0; o < 4; ++o) {
        const float g = sigmoidf(ag[o] + bg2);         // node gate: bias gbs[:,2]
        res[o] = out1[o] + n0c[o] * g + n1v[o] * (1.f - g);
    }
    float* oplane = out + (size_t)plane * (OHW * OHW);
    *reinterpret_cast<float2*>(&oplane[grA * OHW + 2 * p])       = make_float2(res[0], res[1]);
    *reinterpret_cast<float2*>(&oplane[(grA + 1) * OHW + 2 * p]) = make_float2(res[2], res[3]);
}

extern "C" void kernel_launch(void* const* d_in, const int* in_sizes, int n_in,
                              void* d_out, int out_size, void* d_ws, size_t ws_size,
                              hipStream_t stream) {
    const float* x       = (const float*)d_in[0];
    const float* maxgate = (const float*)d_in[1];
    const float* mb      = (const float*)d_in[2];
    const float* pconvs  = (const float*)d_in[3];
    const float* pbs     = (const float*)d_in[4];
    const float* pgates  = (const float*)d_in[5];
    const float* gbs     = (const float*)d_in[6];
    float* out           = (float*)d_out;

    const int blocks = 16 * 256 * NT;   // B * C * tiles-per-plane
    fused_densenet_kernel<<<blocks, TB, 0, stream>>>(
        x, maxgate, mb, pconvs, pbs, pgates, gbs, out);
}